// Round 11
// baseline (705.832 us; speedup 1.0000x reference)
//
#include <hip/hip_runtime.h>
#include <math.h>

#define N_NODES 30000
#define N_EDGES 480000
#define HEADS   6
#define NN2 (2 * N_NODES)
#define NE2 (2 * N_EDGES)

typedef __attribute__((ext_vector_type(8))) short bf16x8;
typedef __attribute__((ext_vector_type(4))) float f32x4;
typedef __attribute__((ext_vector_type(2))) float f32x2;
typedef __attribute__((ext_vector_type(4))) unsigned u32x4;

// ---------- bf16 helper (agg outputs feeding next GEMM's A-operand) ----------
__device__ __forceinline__ unsigned short f2bf(float f) {
    unsigned u = __float_as_uint(f);
    u += 0x7fffu + ((u >> 16) & 1u);   // RNE
    return (unsigned short)(u >> 16);
}

// ---------- layer-1 GEMM (K=11, VALU) fused with es/ed + fp8-z epilogue ----------
// z stored HEAD-MAJOR: zf8b[((h*NN2)+node)*Fo + fo].
__global__ void gemm1_es_kernel(const float* __restrict__ x0, const float* __restrict__ x1,
                                const float* __restrict__ W, const float* __restrict__ a_s,
                                const float* __restrict__ a_d,
                                unsigned char* __restrict__ zf8b, float* __restrict__ es8,
                                float* __restrict__ ed8) {
    constexpr int K = 11, HF = 96, TM = 16, Fo = 16;
    __shared__ float hs[TM * K];
    const int m0 = blockIdx.x * TM;
    const float* h = (m0 < N_NODES) ? (x0 + (size_t)m0 * K)
                                    : (x1 + (size_t)(m0 - N_NODES) * K);
    const int j = blockIdx.y * 64 + threadIdx.x;
    for (int idx = threadIdx.x; idx < TM * K; idx += 64) hs[idx] = h[idx];
    __syncthreads();
    if (j >= HF) return;
    float acc[TM];
#pragma unroll
    for (int m = 0; m < TM; ++m) acc[m] = 0.f;
    for (int k = 0; k < K; ++k) {
        float w = W[k * HF + j];
#pragma unroll
        for (int m = 0; m < TM; ++m) acc[m] = fmaf(hs[m * K + k], w, acc[m]);
    }
    const float as_v = a_s[j];
    const float ad_v = a_d[j];
    const int hh = j >> 4;          // head = col/16 (Fo=16)
    const int fo = j & 15;
#pragma unroll
    for (int m = 0; m < TM; ++m) {
        const int pk = __builtin_amdgcn_cvt_pk_fp8_f32(acc[m], acc[m], 0, false);
        zf8b[((size_t)hh * NN2 + (m0 + m)) * Fo + fo] = (unsigned char)pk;
    }
#pragma unroll
    for (int m = 0; m < TM; ++m) {
        float ep = acc[m] * as_v;
        float dp = acc[m] * ad_v;
#pragma unroll
        for (int d = 1; d < 16; d <<= 1) {
            ep += __shfl_xor(ep, d);
            dp += __shfl_xor(dp, d);
        }
        if ((threadIdx.x & 15) == 0) {
            es8[(size_t)(m0 + m) * 8 + hh] = ep;
            ed8[(size_t)(m0 + m) * 8 + hh] = dp;
        }
    }
}

// ---------- W -> Wt (transposed, bf16) ----------
__global__ void convert_wt_kernel(const float* __restrict__ W, unsigned short* __restrict__ Wt,
                                  int K, int HF) {
    const int idx = blockIdx.x * 256 + threadIdx.x;
    if (idx >= K * HF) return;
    const int k = idx / HF;
    const int n = idx - k * HF;
    Wt[n * K + k] = f2bf(W[idx]);
}

// ---------- MFMA GEMM fused with es/ed + fp8-z epilogue (head-major z) ----------
// Round-10 proven: block-cooperative LDS staging of the B tile, reg-prefetched
// one tile ahead; all waves stay in the loop (barrier-safe), `active` guards stores.
template <int K, int HF>
__global__ __launch_bounds__(256) void gemm_es_kernel(
        const unsigned short* __restrict__ hbf, const unsigned short* __restrict__ Wt,
        const float* __restrict__ a_s, const float* __restrict__ a_d,
        unsigned char* __restrict__ zf8b, float* __restrict__ es8,
        float* __restrict__ ed8) {
    constexpr int KSTEPS = K / 32;
    constexpr int Fo  = HF / HEADS;
    constexpr int TPH = Fo / 16;        // tiles per head
    constexpr int NT  = HF / 16;        // N tiles
    constexpr int PAD = 8;              // shorts; row stride K+8 -> balanced banks
    constexpr int LROW = K + PAD;
    constexpr int NCH = 16 * K / 8;     // 16B chunks per B tile
    __shared__ unsigned short bl[16 * LROW];

    const int tid  = threadIdx.x;
    const int wid  = blockIdx.x * 4 + (tid >> 6);
    const bool active = wid < NN2 / 16;
    const int lane = tid & 63;
    const int r16  = lane & 15;
    const int quad = lane >> 4;
    const int m0 = active ? wid * 16 : 0;

    bf16x8 afrag[KSTEPS];
    const unsigned short* ap = hbf + (size_t)(m0 + r16) * K + quad * 8;
#pragma unroll
    for (int i = 0; i < KSTEPS; ++i) afrag[i] = *(const bf16x8*)(ap + i * 32);

    // prefetch B tile 0 into regs (<=2 chunks of 16B per thread)
    u32x4 st[2];
#pragma unroll
    for (int j = 0; j < 2; ++j) {
        const int c = tid + j * 256;
        if (c < NCH) st[j] = *(const u32x4*)(Wt + (size_t)c * 8);
    }

    float es_p[4] = {0.f, 0.f, 0.f, 0.f};
    float ed_p[4] = {0.f, 0.f, 0.f, 0.f};
    for (int t = 0; t < NT; ++t) {
        __syncthreads();                 // prior tile's reads complete
#pragma unroll
        for (int j = 0; j < 2; ++j) {    // write staged tile t
            const int c = tid + j * 256;
            if (c < NCH) {
                const int row = c / (K / 8);
                const int co  = c - row * (K / 8);
                *(u32x4*)(bl + row * LROW + co * 8) = st[j];
            }
        }
        if (t + 1 < NT) {                // prefetch tile t+1
            const unsigned short* wp = Wt + (size_t)(t + 1) * 16 * K;
#pragma unroll
            for (int j = 0; j < 2; ++j) {
                const int c = tid + j * 256;
                if (c < NCH) st[j] = *(const u32x4*)(wp + (size_t)c * 8);
            }
        }
        __syncthreads();                 // tile t visible

        f32x4 acc = {0.f, 0.f, 0.f, 0.f};
        const unsigned short* bp = bl + r16 * LROW + quad * 8;
#pragma unroll
        for (int i = 0; i < KSTEPS; ++i) {
            const bf16x8 bfrag = *(const bf16x8*)(bp + i * 32);
            acc = __builtin_amdgcn_mfma_f32_16x16x32_bf16(afrag[i], bfrag, acc, 0, 0, 0);
        }
        const float as_v = a_s[t * 16 + r16];
        const float ad_v = a_d[t * 16 + r16];
        const int th = t / TPH;                       // head of this tile
        const int fo = (t % TPH) * 16 + r16;          // feat within head
        unsigned char* zp = zf8b + ((size_t)th * NN2 + (m0 + quad * 4)) * Fo + fo;
#pragma unroll
        for (int r = 0; r < 4; ++r) {
            const int pk = __builtin_amdgcn_cvt_pk_fp8_f32(acc[r], acc[r], 0, false);
            if (active) zp[(size_t)r * Fo] = (unsigned char)pk;
            es_p[r] = fmaf(acc[r], as_v, es_p[r]);
            ed_p[r] = fmaf(acc[r], ad_v, ed_p[r]);
        }
        if (((t + 1) % TPH) == 0) {     // head boundary: reduce + store + reset
            const int h = t / TPH;
#pragma unroll
            for (int r = 0; r < 4; ++r) {
                float ep = es_p[r], dp = ed_p[r];
#pragma unroll
                for (int d = 1; d < 16; d <<= 1) {
                    ep += __shfl_xor(ep, d);
                    dp += __shfl_xor(dp, d);
                }
                if (active && r16 == 0) {
                    es8[(size_t)(m0 + quad * 4 + r) * 8 + h] = ep;
                    ed8[(size_t)(m0 + quad * 4 + r) * 8 + h] = dp;
                }
                es_p[r] = 0.f;
                ed_p[r] = 0.f;
            }
        }
    }
}

// ---------- CSR build (both graphs, global node ids; packed {dst|src} u32) ------
__global__ void zero_int_kernel(int* __restrict__ p, int n) {
    const int i = blockIdx.x * 256 + threadIdx.x;
    if (i < n) p[i] = 0;
}

__global__ void hist2_kernel(const int* __restrict__ ei0, const int* __restrict__ ei1,
                             int* __restrict__ cnt) {
    const int e = blockIdx.x * 256 + threadIdx.x;
    if (e >= NE2) return;
    const int g = e >= N_EDGES;
    const int* ei = g ? ei1 : ei0;
    const int e2 = e - g * N_EDGES;
    atomicAdd(&cnt[g * N_NODES + ei[N_EDGES + e2]], 1);
}

#define SCAN_NB ((NN2 + 1023) / 1024)
__global__ void scan1_kernel(int* tmp, int* __restrict__ bsum) {
    __shared__ int s[1024];
    const int t = threadIdx.x;
    const int gid = blockIdx.x * 1024 + t;
    const int v = (gid < NN2) ? tmp[gid] : 0;
    s[t] = v;
    __syncthreads();
    for (int d = 1; d < 1024; d <<= 1) {
        int x = (t >= d) ? s[t - d] : 0;
        __syncthreads();
        s[t] += x;
        __syncthreads();
    }
    tmp[gid] = s[t] - v;                 // in-place: cnt -> exclusive prefix
    if (t == 1023) bsum[blockIdx.x] = s[1023];
}

__global__ void scan2_kernel(int* __restrict__ bsum, int* __restrict__ boff) {
    if (threadIdx.x == 0) {
        int a = 0;
        for (int i = 0; i < SCAN_NB; ++i) { boff[i] = a; a += bsum[i]; }
        boff[SCAN_NB] = a;
    }
}

__global__ void scan3_kernel(int* tmp, const int* __restrict__ boff,
                             int* __restrict__ off) {
    const int gid = blockIdx.x * 1024 + threadIdx.x;
    if (gid < NN2) {
        const int o = tmp[gid] + boff[gid >> 10];
        off[gid] = o;
        tmp[gid] = o;                    // in-place: prefix -> cursor
    }
    if (gid == 0) off[NN2] = boff[SCAN_NB];
}

// one u32 store per edge ({dst:16|src:16}) -> half the write-allocate line traffic
__global__ void scatter2_kernel(const int* __restrict__ ei0, const int* __restrict__ ei1,
                                int* __restrict__ cursor,
                                unsigned* __restrict__ csrp) {
    const int e = blockIdx.x * 256 + threadIdx.x;
    if (e >= NE2) return;
    const int g = e >= N_EDGES;
    const int* ei = g ? ei1 : ei0;
    const int e2 = e - g * N_EDGES;
    const int src = g * N_NODES + ei[e2];           // < 60000, fits u16
    const int dst = g * N_NODES + ei[N_EDGES + e2];
    const int slot = atomicAdd(&cursor[dst], 1);
    csrp[slot] = ((unsigned)dst << 16) | (unsigned)src;
}

// ---------- degree counting sort (per graph) --------------------------------
// Any permutation is CORRECT (agg output indexed by actual node id; pool is a sum);
// sorting only equalizes per-wave degrees to kill lockstep-divergence waste.
// Buckets: g*512 + min(deg,511). Graph-0 buckets scan first -> positions
// [0,N_NODES) are graph-0, so position-based graph tests stay valid.
__global__ void deghist_kernel(const int* __restrict__ off, int* __restrict__ dbuk) {
    const int n = blockIdx.x * 256 + threadIdx.x;
    if (n >= NN2) return;
    const int deg = off[n + 1] - off[n];
    const int b = deg < 511 ? deg : 511;
    atomicAdd(&dbuk[(n >= N_NODES) * 512 + b], 1);
}

__global__ void degscan_kernel(int* __restrict__ dbuk) {
    __shared__ int s[1024];
    const int t = threadIdx.x;
    const int v = dbuk[t];
    s[t] = v;
    __syncthreads();
    for (int d = 1; d < 1024; d <<= 1) {
        int x = (t >= d) ? s[t - d] : 0;
        __syncthreads();
        s[t] += x;
        __syncthreads();
    }
    dbuk[t] = s[t] - v;                  // exclusive prefix = bucket cursor base
}

__global__ void degscatter_kernel(const int* __restrict__ off, int* __restrict__ dbuk,
                                  unsigned short* __restrict__ sorted) {
    const int n = blockIdx.x * 256 + threadIdx.x;
    if (n >= NN2) return;
    const int deg = off[n + 1] - off[n];
    const int b = deg < 511 ? deg : 511;
    const int pos = atomicAdd(&dbuk[(n >= N_NODES) * 512 + b], 1);
    sorted[pos] = (unsigned short)n;
}

// ---------- per-(edge,head) attention weight precompute ----------
__global__ __launch_bounds__(256) void edgew_kernel(
        const unsigned* __restrict__ csrp,
        const float* __restrict__ es8, const float* __restrict__ ed8,
        unsigned* __restrict__ pA, unsigned* __restrict__ pB) {
    const int s = blockIdx.x * 256 + threadIdx.x;
    if (s >= NE2) return;
    const unsigned sd = csrp[s];
    const unsigned src = sd & 0xFFFFu;
    const unsigned dst = sd >> 16;
    const f32x4 ea = *(const f32x4*)(es8 + src * 8u);
    const f32x2 eb = *(const f32x2*)(es8 + src * 8u + 4);
    const f32x4 da = *(const f32x4*)(ed8 + dst * 8u);
    const f32x2 db = *(const f32x2*)(ed8 + dst * 8u + 4);
    float ev[6];
    ev[0] = ea.x + da.x; ev[1] = ea.y + da.y; ev[2] = ea.z + da.z;
    ev[3] = ea.w + da.w; ev[4] = eb.x + db.x; ev[5] = eb.y + db.y;
#pragma unroll
    for (int h = 0; h < 6; ++h) {
        float v = ev[h];
        v = fmaxf(v, 0.2f * v);
        const unsigned rec = ((unsigned)f2bf(__expf(v)) << 16) | src;
        unsigned* p = (h < 3) ? (pA + (size_t)h * NE2) : (pB + (size_t)(h - 3) * NE2);
        p[s] = rec;
    }
}

// ---------- layer aggs: sub-wave node-head groups, BATCHED loads, SORTED nodes --
template <int HF, int GS, int MAIN, int G>
__global__ __launch_bounds__(256) void agg_sub_kernel(
        const int* __restrict__ off, const unsigned short* __restrict__ sorted,
        const unsigned* __restrict__ ewA, const unsigned* __restrict__ ewB,
        const unsigned* __restrict__ zf8, unsigned short* __restrict__ outz) {
    constexpr int Fo  = HF / HEADS;
    constexpr int L   = Fo / 4;          // feat-dword lanes per edge
    constexpr int EPI = GS / L;          // edges in parallel (4)
    constexpr int GPW = 64 / GS;         // node-heads per wave
    constexpr int NB  = 4 * GPW;         // node-heads per block
    constexpr int BPH = NN2 / NB;        // blocks per head
    int h, blk;
    {
        const int r = blockIdx.x & 7, g = blockIdx.x >> 3;
        if (r < 6) {
            if (g >= MAIN) return;
            h = r; blk = g;
        } else {
            const int k = (r - 6) * G + g;
            if (k >= 6 * (BPH - MAIN)) return;
            h = k % 6; blk = MAIN + k / 6;
        }
    }
    const int wavid = threadIdx.x >> 6;
    const int lane  = threadIdx.x & 63;
    const int grp = lane / GS;           // node-head group within wave
    const int lg  = lane - grp * GS;
    const int eo = lg / L;
    const int fp = lg - eo * L;
    const int npos = blk * NB + wavid * GPW + grp;
    const int n = sorted[npos];          // degree-sorted indirection

    const int s0  = off[n];
    const int deg = off[n + 1] - s0;
    const unsigned* ewp = ((h < 3) ? (ewA + (size_t)h * NE2)
                                   : (ewB + (size_t)(h - 3) * NE2)) + s0;
    const unsigned* zh = zf8 + (size_t)h * ((size_t)NN2 * L);

    float a0 = 0.f, a1 = 0.f, a2 = 0.f, a3 = 0.f, lsum = 0.f;
    for (int ib = 0; ib < deg; ib += 4 * EPI) {
        unsigned rec[4];
#pragma unroll
        for (int k = 0; k < 4; ++k) {
            const int idx = ib + k * EPI + eo;
            rec[k] = ewp[idx < deg ? idx : 0];
        }
        unsigned zz[4];
#pragma unroll
        for (int k = 0; k < 4; ++k)
            zz[k] = zh[(rec[k] & 0xFFFFu) * (unsigned)L + (unsigned)fp];
#pragma unroll
        for (int k = 0; k < 4; ++k) {
            const int idx = ib + k * EPI + eo;
            float ww = __uint_as_float(rec[k] & 0xFFFF0000u);
            ww = (idx < deg) ? ww : 0.f;
            lsum += ww;
            const f32x2 lo = __builtin_amdgcn_cvt_pk_f32_fp8((int)zz[k], false);
            const f32x2 hi = __builtin_amdgcn_cvt_pk_f32_fp8((int)zz[k], true);
            a0 = fmaf(ww, lo.x, a0);
            a1 = fmaf(ww, lo.y, a1);
            a2 = fmaf(ww, hi.x, a2);
            a3 = fmaf(ww, hi.y, a3);
        }
    }
#pragma unroll
    for (int d = L; d < GS; d <<= 1) {   // reduce within GS-group only
        a0 += __shfl_xor(a0, d);
        a1 += __shfl_xor(a1, d);
        a2 += __shfl_xor(a2, d);
        a3 += __shfl_xor(a3, d);
        lsum += __shfl_xor(lsum, d);
    }
    if (eo == 0) {
        const float inv = 1.f / (lsum + 1e-16f);
        float o0 = a0 * inv, o1 = a1 * inv, o2 = a2 * inv, o3 = a3 * inv;
        o0 = o0 > 0.f ? o0 : (__expf(o0) - 1.f);
        o1 = o1 > 0.f ? o1 : (__expf(o1) - 1.f);
        o2 = o2 > 0.f ? o2 : (__expf(o2) - 1.f);
        o3 = o3 > 0.f ? o3 : (__expf(o3) - 1.f);
        unsigned short* op = outz + (size_t)n * HF + h * Fo + 4 * fp;
        *(unsigned*)op       = (unsigned)f2bf(o0) | ((unsigned)f2bf(o1) << 16);
        *(unsigned*)(op + 2) = (unsigned)f2bf(o2) | ((unsigned)f2bf(o3) << 16);
    }
}

// ---------- layer-3 aggregation fused with sum pooling: 16-chain + sorted -------
#define POOL_BLOCKS 3072
#define POOL_WAVES 2048
__global__ __launch_bounds__(256) void agg_pool_kernel(
        const int* __restrict__ off, const unsigned short* __restrict__ sorted,
        const unsigned* __restrict__ ewA, const unsigned* __restrict__ ewB,
        const unsigned* __restrict__ zf8, float* __restrict__ pooled) {
    __shared__ float lds[128];
    int h, slot;
    {
        const int r = blockIdx.x & 7, g = blockIdx.x >> 3;   // g in [0,384)
        if (r < 6) { h = r; slot = g; }
        else { h = g % 6; slot = 384 + (r - 6) * 64 + g / 6; }
    }
    const int wavid = threadIdx.x >> 6;
    const int ws    = slot * 4 + wavid;          // [0,2048)
    const int lane  = threadIdx.x & 63;
    const int c  = lane >> 2;                    // chain within wave, 0..15
    const int fp = lane & 3;                     // dwordx4 slice -> feats fp*16..fp*16+15
    const unsigned* ewh = (h < 3) ? (ewA + (size_t)h * NE2)
                                  : (ewB + (size_t)(h - 3) * NE2);
    const u32x4* zq = (const u32x4*)(zf8 + (size_t)h * ((size_t)NN2 * 16));

    if (threadIdx.x < 128) lds[threadIdx.x] = 0.f;
    __syncthreads();

    float p0[16], p1[16];
#pragma unroll
    for (int j = 0; j < 16; ++j) { p0[j] = 0.f; p1[j] = 0.f; }

    for (int base = ws * 16; base < NN2; base += POOL_WAVES * 16) {
        const int npos = base + c;               // base%16==0, NN2%16==0 -> in range
        const int n = sorted[npos];              // degree-sorted indirection
        const int s0  = off[n];
        const int deg = off[n + 1] - s0;
        int dmx = deg;
#pragma unroll
        for (int d = 4; d < 64; d <<= 1) {       // wave-max degree (~=deg after sort)
            const int o = __shfl_xor(dmx, d);
            dmx = o > dmx ? o : dmx;
        }
        const unsigned* ewp = ewh + s0;
        float acc[16];
#pragma unroll
        for (int j = 0; j < 16; ++j) acc[j] = 0.f;
        float lsum = 0.f;
        for (int ib = 0; ib < dmx; ib += 4) {
            unsigned rec[4];
#pragma unroll
            for (int k = 0; k < 4; ++k) {
                const int idx = ib + k;
                rec[k] = ewp[idx < deg ? idx : 0];
            }
            u32x4 zz[4];
#pragma unroll
            for (int k = 0; k < 4; ++k)
                zz[k] = zq[(rec[k] & 0xFFFFu) * 4u + (unsigned)fp];
#pragma unroll
            for (int k = 0; k < 4; ++k) {
                float w = __uint_as_float(rec[k] & 0xFFFF0000u);
                w = ((ib + k) < deg) ? w : 0.f;
                lsum += w;
#pragma unroll
                for (int d = 0; d < 4; ++d) {
                    const f32x2 lo = __builtin_amdgcn_cvt_pk_f32_fp8((int)zz[k][d], false);
                    const f32x2 hi = __builtin_amdgcn_cvt_pk_f32_fp8((int)zz[k][d], true);
                    acc[4 * d + 0] = fmaf(w, lo.x, acc[4 * d + 0]);
                    acc[4 * d + 1] = fmaf(w, lo.y, acc[4 * d + 1]);
                    acc[4 * d + 2] = fmaf(w, hi.x, acc[4 * d + 2]);
                    acc[4 * d + 3] = fmaf(w, hi.y, acc[4 * d + 3]);
                }
            }
        }
        {
            const float inv = 1.f / (lsum + 1e-16f);
            if (base < N_NODES) {                // positions partition by graph
#pragma unroll
                for (int j = 0; j < 16; ++j) {
                    float o = acc[j] * inv;
                    o = o > 0.f ? o : (__expf(o) - 1.f);
                    p0[j] += o;
                }
            } else {
#pragma unroll
                for (int j = 0; j < 16; ++j) {
                    float o = acc[j] * inv;
                    o = o > 0.f ? o : (__expf(o) - 1.f);
                    p1[j] += o;
                }
            }
        }
    }
    // one butterfly per kernel: reduce pooled sums across the 16 chains
#pragma unroll
    for (int d = 4; d < 64; d <<= 1) {
#pragma unroll
        for (int j = 0; j < 16; ++j) {
            p0[j] += __shfl_xor(p0[j], d);
            p1[j] += __shfl_xor(p1[j], d);
        }
    }
    if (lane < 4) {                              // fp == lane here
#pragma unroll
        for (int j = 0; j < 16; ++j) {
            atomicAdd(&lds[fp * 16 + j], p0[j]);
            atomicAdd(&lds[64 + fp * 16 + j], p1[j]);
        }
    }
    __syncthreads();
    if (threadIdx.x < 128) {
        const int g2 = threadIdx.x >> 6;
        const int f  = threadIdx.x & 63;
        atomicAdd(&pooled[g2 * 384 + h * 64 + f], lds[threadIdx.x]);
    }
}

__global__ void zero_pooled_kernel(float* __restrict__ p) {
    const int i = blockIdx.x * 256 + threadIdx.x;
    if (i < 768) p[i] = 0.f;
}

__global__ void final_kernel(const float* __restrict__ pooled, const float* __restrict__ Wd,
                             const float* __restrict__ bd, float* __restrict__ outp) {
    __shared__ float s_ss[256], s_dot[256];
    const int t = threadIdx.x;
    float ss = 0.f, dot = 0.f;
    for (int c = t; c < 768; c += 256) {
        const float v = pooled[c];
        ss  = fmaf(v, v, ss);
        dot = fmaf(v, Wd[c], dot);
    }
    s_ss[t] = ss; s_dot[t] = dot;
    __syncthreads();
    for (int off = 128; off > 0; off >>= 1) {
        if (t < off) { s_ss[t] += s_ss[t + off]; s_dot[t] += s_dot[t + off]; }
        __syncthreads();
    }
    if (t == 0) {
        const float norm = fmaxf(sqrtf(s_ss[0]), 1e-12f);
        outp[0] = s_dot[0] / norm + bd[0];
    }
}

extern "C" void kernel_launch(void* const* d_in, const int* in_sizes, int n_in,
                              void* d_out, int out_size, void* d_ws, size_t ws_size,
                              hipStream_t stream) {
    const float* x_int = (const float*)d_in[0];
    const float* x_nh  = (const float*)d_in[1];
    const int*   ei_int = (const int*)d_in[2];
    const int*   ei_nh  = (const int*)d_in[3];
    const float* W1  = (const float*)d_in[4];
    const float* a1s = (const float*)d_in[5];
    const float* a1d = (const float*)d_in[6];
    const float* W2  = (const float*)d_in[7];
    const float* a2s = (const float*)d_in[8];
    const float* a2d = (const float*)d_in[9];
    const float* W3  = (const float*)d_in[10];
    const float* a3s = (const float*)d_in[11];
    const float* a3d = (const float*)d_in[12];
    const float* Wd  = (const float*)d_in[13];
    const float* bd  = (const float*)d_in[14];
    float* out = (float*)d_out;

    // workspace layout (16B-aligned sections); total ~63.0 MiB
    unsigned short* hbf_a = (unsigned short*)d_ws;                 // NN2*96  bf16 (11.52 MB)
    unsigned short* hbf_b = hbf_a + (size_t)NN2 * 96;              // NN2*192 bf16 (23.04 MB)
    unsigned short* wt2   = hbf_b + (size_t)NN2 * 192;             // 192*96
    unsigned short* wt3   = wt2   + (size_t)96 * 192;              // 384*192
    unsigned* zf8 = (unsigned*)(wt3 + (size_t)192 * 384);          // NN2*96 dwords (fp8, head-major)
    float* es8   = (float*)(zf8 + (size_t)NN2 * 96);               // NN2*8 ([node][head])
    float* ed8   = es8 + (size_t)NN2 * 8;                          // NN2*8
    float* pooled = ed8 + (size_t)NN2 * 8;                         // 768
    int* tmp     = (int*)(pooled + 768);                           // SCAN_NB*1024 (cnt/prefix/cursor/dbuk)
    int* bsum    = tmp + SCAN_NB * 1024;                           // SCAN_NB
    int* boff    = bsum + SCAN_NB;                                 // SCAN_NB+1
    int* off     = boff + SCAN_NB + 1;                             // NN2+1
    unsigned* csrp = (unsigned*)(off + NN2 + 1);                   // NE2 u32 ({dst|src})
    unsigned short* sorted = (unsigned short*)(csrp + NE2);        // NN2 u16 (deg-sorted nodes)
    unsigned char* zf8b = (unsigned char*)zf8;

    // u32 ew planes (6*NE2*4 = 23.04 MB), aliased into DEAD buffer windows:
    //  layers 1,3: all 6 planes in hbf_b; layer 2: planes 0-2 in hbf_a,
    //  planes 3-5 in zf8 tail (layer-2 z fills only first NN2*48 dwords)
    unsigned* ew13A = (unsigned*)hbf_b;
    unsigned* ew13B = ew13A + (size_t)3 * NE2;
    unsigned* ew2A  = (unsigned*)hbf_a;
    unsigned* ew2B  = zf8 + (size_t)NN2 * 48;

    zero_pooled_kernel<<<3, 256, 0, stream>>>(pooled);
    convert_wt_kernel<<<(96 * 192 + 255) / 256, 256, 0, stream>>>(W2, wt2, 96, 192);
    convert_wt_kernel<<<(192 * 384 + 255) / 256, 256, 0, stream>>>(W3, wt3, 192, 384);

    // batched CSR over both graphs
    zero_int_kernel<<<(NN2 + 255) / 256, 256, 0, stream>>>(tmp, NN2);
    hist2_kernel<<<(NE2 + 255) / 256, 256, 0, stream>>>(ei_int, ei_nh, tmp);
    scan1_kernel<<<SCAN_NB, 1024, 0, stream>>>(tmp, bsum);
    scan2_kernel<<<1, 64, 0, stream>>>(bsum, boff);
    scan3_kernel<<<SCAN_NB, 1024, 0, stream>>>(tmp, boff, off);
    scatter2_kernel<<<(NE2 + 255) / 256, 256, 0, stream>>>(ei_int, ei_nh, tmp, csrp);

    // degree counting sort (tmp is dead after scatter2; reuse as buckets/cursors)
    zero_int_kernel<<<4, 256, 0, stream>>>(tmp, 1024);
    deghist_kernel<<<(NN2 + 255) / 256, 256, 0, stream>>>(off, tmp);
    degscan_kernel<<<1, 1024, 0, stream>>>(tmp);
    degscatter_kernel<<<(NN2 + 255) / 256, 256, 0, stream>>>(off, tmp, sorted);

    const int mfma_blocks = (NN2 / 16 + 3) / 4;
    const int ew_blocks = (NE2 + 255) / 256;

    // layer 1: VALU GEMM + fused es/ed + fp8 z; edge records; agg GS=16 (sorted)
    gemm1_es_kernel<<<dim3(NN2 / 16, 2), 64, 0, stream>>>(x_int, x_nh, W1, a1s, a1d, zf8b,
                                                          es8, ed8);
    edgew_kernel<<<ew_blocks, 256, 0, stream>>>(csrp, es8, ed8, ew13A, ew13B);
    agg_sub_kernel<96, 16, 2812, 2814><<<8 * 2814, 256, 0, stream>>>(off, sorted, ew13A,
                                                                     ew13B, zf8, hbf_a);
    // layer 2: MFMA GEMM (LDS-staged B) + fused epilogue; agg GS=32 (sorted)
    gemm_es_kernel<96, 192><<<mfma_blocks, 256, 0, stream>>>(hbf_a, wt2, a2s, a2d, zf8b,
                                                             es8, ed8);
    edgew_kernel<<<ew_blocks, 256, 0, stream>>>(csrp, es8, ed8, ew2A, ew2B);
    agg_sub_kernel<192, 32, 5625, 5625><<<45000, 256, 0, stream>>>(off, sorted, ew2A,
                                                                   ew2B, zf8, hbf_b);
    // layer 3: MFMA GEMM (LDS-staged B) + fused epilogue; 16-chain agg+pool (sorted)
    gemm_es_kernel<192, 384><<<mfma_blocks, 256, 0, stream>>>(hbf_b, wt3, a3s, a3d, zf8b,
                                                              es8, ed8);
    edgew_kernel<<<ew_blocks, 256, 0, stream>>>(csrp, es8, ed8, ew13A, ew13B);
    agg_pool_kernel<<<POOL_BLOCKS, 256, 0, stream>>>(off, sorted, ew13A, ew13B, zf8,
                                                     pooled);

    final_kernel<<<1, 256, 0, stream>>>(pooled, Wd, bd, out);
}

// Round 12
// 488.532 us; speedup vs baseline: 1.4448x; 1.4448x over previous
//
#include <hip/hip_runtime.h>
#include <math.h>

#define N_NODES 30000
#define N_EDGES 480000
#define HEADS   6
#define NN2 (2 * N_NODES)
#define NE2 (2 * N_EDGES)

typedef __attribute__((ext_vector_type(8))) short bf16x8;
typedef __attribute__((ext_vector_type(4))) float f32x4;
typedef __attribute__((ext_vector_type(2))) float f32x2;
typedef __attribute__((ext_vector_type(4))) unsigned u32x4;

// ---------- bf16 helper (agg outputs feeding next GEMM's A-operand) ----------
__device__ __forceinline__ unsigned short f2bf(float f) {
    unsigned u = __float_as_uint(f);
    u += 0x7fffu + ((u >> 16) & 1u);   // RNE
    return (unsigned short)(u >> 16);
}

// ---------- layer-1 GEMM (K=11, VALU) fused with es/ed + fp8-z epilogue ----------
// z stored HEAD-MAJOR: zf8b[((h*NN2)+node)*Fo + fo].
__global__ void gemm1_es_kernel(const float* __restrict__ x0, const float* __restrict__ x1,
                                const float* __restrict__ W, const float* __restrict__ a_s,
                                const float* __restrict__ a_d,
                                unsigned char* __restrict__ zf8b, float* __restrict__ es8,
                                float* __restrict__ ed8) {
    constexpr int K = 11, HF = 96, TM = 16, Fo = 16;
    __shared__ float hs[TM * K];
    const int m0 = blockIdx.x * TM;
    const float* h = (m0 < N_NODES) ? (x0 + (size_t)m0 * K)
                                    : (x1 + (size_t)(m0 - N_NODES) * K);
    const int j = blockIdx.y * 64 + threadIdx.x;
    for (int idx = threadIdx.x; idx < TM * K; idx += 64) hs[idx] = h[idx];
    __syncthreads();
    if (j >= HF) return;
    float acc[TM];
#pragma unroll
    for (int m = 0; m < TM; ++m) acc[m] = 0.f;
    for (int k = 0; k < K; ++k) {
        float w = W[k * HF + j];
#pragma unroll
        for (int m = 0; m < TM; ++m) acc[m] = fmaf(hs[m * K + k], w, acc[m]);
    }
    const float as_v = a_s[j];
    const float ad_v = a_d[j];
    const int hh = j >> 4;          // head = col/16 (Fo=16)
    const int fo = j & 15;
#pragma unroll
    for (int m = 0; m < TM; ++m) {
        const int pk = __builtin_amdgcn_cvt_pk_fp8_f32(acc[m], acc[m], 0, false);
        zf8b[((size_t)hh * NN2 + (m0 + m)) * Fo + fo] = (unsigned char)pk;
    }
#pragma unroll
    for (int m = 0; m < TM; ++m) {
        float ep = acc[m] * as_v;
        float dp = acc[m] * ad_v;
#pragma unroll
        for (int d = 1; d < 16; d <<= 1) {
            ep += __shfl_xor(ep, d);
            dp += __shfl_xor(dp, d);
        }
        if ((threadIdx.x & 15) == 0) {
            es8[(size_t)(m0 + m) * 8 + hh] = ep;
            ed8[(size_t)(m0 + m) * 8 + hh] = dp;
        }
    }
}

// ---------- W -> Wt (transposed, bf16) ----------
__global__ void convert_wt_kernel(const float* __restrict__ W, unsigned short* __restrict__ Wt,
                                  int K, int HF) {
    const int idx = blockIdx.x * 256 + threadIdx.x;
    if (idx >= K * HF) return;
    const int k = idx / HF;
    const int n = idx - k * HF;
    Wt[n * K + k] = f2bf(W[idx]);
}

// ---------- MFMA GEMM fused with es/ed + fp8-z epilogue (head-major z) ----------
// Round-10 proven: block-cooperative LDS staging of the B tile, reg-prefetched
// one tile ahead; all waves stay in the loop (barrier-safe), `active` guards stores.
template <int K, int HF>
__global__ __launch_bounds__(256) void gemm_es_kernel(
        const unsigned short* __restrict__ hbf, const unsigned short* __restrict__ Wt,
        const float* __restrict__ a_s, const float* __restrict__ a_d,
        unsigned char* __restrict__ zf8b, float* __restrict__ es8,
        float* __restrict__ ed8) {
    constexpr int KSTEPS = K / 32;
    constexpr int Fo  = HF / HEADS;
    constexpr int TPH = Fo / 16;        // tiles per head
    constexpr int NT  = HF / 16;        // N tiles
    constexpr int PAD = 8;              // shorts; row stride K+8 -> balanced banks
    constexpr int LROW = K + PAD;
    constexpr int NCH = 16 * K / 8;     // 16B chunks per B tile
    __shared__ unsigned short bl[16 * LROW];

    const int tid  = threadIdx.x;
    const int wid  = blockIdx.x * 4 + (tid >> 6);
    const bool active = wid < NN2 / 16;
    const int lane = tid & 63;
    const int r16  = lane & 15;
    const int quad = lane >> 4;
    const int m0 = active ? wid * 16 : 0;

    bf16x8 afrag[KSTEPS];
    const unsigned short* ap = hbf + (size_t)(m0 + r16) * K + quad * 8;
#pragma unroll
    for (int i = 0; i < KSTEPS; ++i) afrag[i] = *(const bf16x8*)(ap + i * 32);

    // prefetch B tile 0 into regs (<=2 chunks of 16B per thread)
    u32x4 st[2];
#pragma unroll
    for (int j = 0; j < 2; ++j) {
        const int c = tid + j * 256;
        if (c < NCH) st[j] = *(const u32x4*)(Wt + (size_t)c * 8);
    }

    float es_p[4] = {0.f, 0.f, 0.f, 0.f};
    float ed_p[4] = {0.f, 0.f, 0.f, 0.f};
    for (int t = 0; t < NT; ++t) {
        __syncthreads();                 // prior tile's reads complete
#pragma unroll
        for (int j = 0; j < 2; ++j) {    // write staged tile t
            const int c = tid + j * 256;
            if (c < NCH) {
                const int row = c / (K / 8);
                const int co  = c - row * (K / 8);
                *(u32x4*)(bl + row * LROW + co * 8) = st[j];
            }
        }
        if (t + 1 < NT) {                // prefetch tile t+1
            const unsigned short* wp = Wt + (size_t)(t + 1) * 16 * K;
#pragma unroll
            for (int j = 0; j < 2; ++j) {
                const int c = tid + j * 256;
                if (c < NCH) st[j] = *(const u32x4*)(wp + (size_t)c * 8);
            }
        }
        __syncthreads();                 // tile t visible

        f32x4 acc = {0.f, 0.f, 0.f, 0.f};
        const unsigned short* bp = bl + r16 * LROW + quad * 8;
#pragma unroll
        for (int i = 0; i < KSTEPS; ++i) {
            const bf16x8 bfrag = *(const bf16x8*)(bp + i * 32);
            acc = __builtin_amdgcn_mfma_f32_16x16x32_bf16(afrag[i], bfrag, acc, 0, 0, 0);
        }
        const float as_v = a_s[t * 16 + r16];
        const float ad_v = a_d[t * 16 + r16];
        const int th = t / TPH;                       // head of this tile
        const int fo = (t % TPH) * 16 + r16;          // feat within head
        unsigned char* zp = zf8b + ((size_t)th * NN2 + (m0 + quad * 4)) * Fo + fo;
#pragma unroll
        for (int r = 0; r < 4; ++r) {
            const int pk = __builtin_amdgcn_cvt_pk_fp8_f32(acc[r], acc[r], 0, false);
            if (active) zp[(size_t)r * Fo] = (unsigned char)pk;
            es_p[r] = fmaf(acc[r], as_v, es_p[r]);
            ed_p[r] = fmaf(acc[r], ad_v, ed_p[r]);
        }
        if (((t + 1) % TPH) == 0) {     // head boundary: reduce + store + reset
            const int h = t / TPH;
#pragma unroll
            for (int r = 0; r < 4; ++r) {
                float ep = es_p[r], dp = ed_p[r];
#pragma unroll
                for (int d = 1; d < 16; d <<= 1) {
                    ep += __shfl_xor(ep, d);
                    dp += __shfl_xor(dp, d);
                }
                if (active && r16 == 0) {
                    es8[(size_t)(m0 + quad * 4 + r) * 8 + h] = ep;
                    ed8[(size_t)(m0 + quad * 4 + r) * 8 + h] = dp;
                }
                es_p[r] = 0.f;
                ed_p[r] = 0.f;
            }
        }
    }
}

// ---------- CSR build (both graphs, global node ids; packed {dst|src} u32) ------
__global__ void zero_int_kernel(int* __restrict__ p, int n) {
    const int i = blockIdx.x * 256 + threadIdx.x;
    if (i < n) p[i] = 0;
}

__global__ void hist2_kernel(const int* __restrict__ ei0, const int* __restrict__ ei1,
                             int* __restrict__ cnt) {
    const int e = blockIdx.x * 256 + threadIdx.x;
    if (e >= NE2) return;
    const int g = e >= N_EDGES;
    const int* ei = g ? ei1 : ei0;
    const int e2 = e - g * N_EDGES;
    atomicAdd(&cnt[g * N_NODES + ei[N_EDGES + e2]], 1);
}

#define SCAN_NB ((NN2 + 1023) / 1024)
__global__ void scan1_kernel(int* tmp, int* __restrict__ bsum) {
    __shared__ int s[1024];
    const int t = threadIdx.x;
    const int gid = blockIdx.x * 1024 + t;
    const int v = (gid < NN2) ? tmp[gid] : 0;
    s[t] = v;
    __syncthreads();
    for (int d = 1; d < 1024; d <<= 1) {
        int x = (t >= d) ? s[t - d] : 0;
        __syncthreads();
        s[t] += x;
        __syncthreads();
    }
    tmp[gid] = s[t] - v;                 // in-place: cnt -> exclusive prefix
    if (t == 1023) bsum[blockIdx.x] = s[1023];
}

__global__ void scan2_kernel(int* __restrict__ bsum, int* __restrict__ boff) {
    if (threadIdx.x == 0) {
        int a = 0;
        for (int i = 0; i < SCAN_NB; ++i) { boff[i] = a; a += bsum[i]; }
        boff[SCAN_NB] = a;
    }
}

__global__ void scan3_kernel(int* tmp, const int* __restrict__ boff,
                             int* __restrict__ off) {
    const int gid = blockIdx.x * 1024 + threadIdx.x;
    if (gid < NN2) {
        const int o = tmp[gid] + boff[gid >> 10];
        off[gid] = o;
        tmp[gid] = o;                    // in-place: prefix -> cursor
    }
    if (gid == 0) off[NN2] = boff[SCAN_NB];
}

// one u32 store per edge ({dst:16|src:16}) -> half the write-allocate line traffic
__global__ void scatter2_kernel(const int* __restrict__ ei0, const int* __restrict__ ei1,
                                int* __restrict__ cursor,
                                unsigned* __restrict__ csrp) {
    const int e = blockIdx.x * 256 + threadIdx.x;
    if (e >= NE2) return;
    const int g = e >= N_EDGES;
    const int* ei = g ? ei1 : ei0;
    const int e2 = e - g * N_EDGES;
    const int src = g * N_NODES + ei[e2];           // < 60000, fits u16
    const int dst = g * N_NODES + ei[N_EDGES + e2];
    const int slot = atomicAdd(&cursor[dst], 1);
    csrp[slot] = ((unsigned)dst << 16) | (unsigned)src;
}

// ---------- WINDOW-LOCAL degree sort (round 12) ------------------------------
// Bitonic-sort each 256-node window by degree. Equalizes per-wave degrees
// (kills lockstep-divergence waste) while keeping CSR/ew streams window-local
// (the r11 global sort's +50MB FETCH regression came from losing locality).
// Any permutation is CORRECT: agg outputs are indexed by the real node id.
__global__ void winsort_kernel(const int* __restrict__ off,
                               unsigned short* __restrict__ sorted) {
    __shared__ unsigned skey[256];
    const int t = threadIdx.x;
    const int n = blockIdx.x * 256 + t;
    unsigned v = 0xFFFFFFFFu;                        // padding sorts to end
    if (n < NN2) {
        int deg = off[n + 1] - off[n];
        if (deg > 65535) deg = 65535;
        v = ((unsigned)deg << 16) | (unsigned)n & 0xFFFFu;
        v = ((unsigned)deg << 16) | ((unsigned)n & 0xFFFFu);
    }
    skey[t] = v;
    for (unsigned k = 2; k <= 256; k <<= 1) {
        for (unsigned j = k >> 1; j > 0; j >>= 1) {
            __syncthreads();
            const unsigned ixj = (unsigned)t ^ j;
            if (ixj > (unsigned)t) {
                const unsigned a = skey[t], b = skey[ixj];
                const bool up = ((t & k) == 0);
                if (up ? (a > b) : (a < b)) { skey[t] = b; skey[ixj] = a; }
            }
        }
    }
    __syncthreads();
    const int pos = blockIdx.x * 256 + t;
    if (pos < NN2) sorted[pos] = (unsigned short)(skey[t] & 0xFFFFu);
}

// ---------- per-(edge,head) attention weight precompute ----------
__global__ __launch_bounds__(256) void edgew_kernel(
        const unsigned* __restrict__ csrp,
        const float* __restrict__ es8, const float* __restrict__ ed8,
        unsigned* __restrict__ pA, unsigned* __restrict__ pB) {
    const int s = blockIdx.x * 256 + threadIdx.x;
    if (s >= NE2) return;
    const unsigned sd = csrp[s];
    const unsigned src = sd & 0xFFFFu;
    const unsigned dst = sd >> 16;
    const f32x4 ea = *(const f32x4*)(es8 + src * 8u);
    const f32x2 eb = *(const f32x2*)(es8 + src * 8u + 4);
    const f32x4 da = *(const f32x4*)(ed8 + dst * 8u);
    const f32x2 db = *(const f32x2*)(ed8 + dst * 8u + 4);
    float ev[6];
    ev[0] = ea.x + da.x; ev[1] = ea.y + da.y; ev[2] = ea.z + da.z;
    ev[3] = ea.w + da.w; ev[4] = eb.x + db.x; ev[5] = eb.y + db.y;
#pragma unroll
    for (int h = 0; h < 6; ++h) {
        float v = ev[h];
        v = fmaxf(v, 0.2f * v);
        const unsigned rec = ((unsigned)f2bf(__expf(v)) << 16) | src;
        unsigned* p = (h < 3) ? (pA + (size_t)h * NE2) : (pB + (size_t)(h - 3) * NE2);
        p[s] = rec;
    }
}

// ---------- layer aggs: sub-wave node-head groups, BATCHED loads, win-sorted ----
template <int HF, int GS, int MAIN, int G>
__global__ __launch_bounds__(256) void agg_sub_kernel(
        const int* __restrict__ off, const unsigned short* __restrict__ sorted,
        const unsigned* __restrict__ ewA, const unsigned* __restrict__ ewB,
        const unsigned* __restrict__ zf8, unsigned short* __restrict__ outz) {
    constexpr int Fo  = HF / HEADS;
    constexpr int L   = Fo / 4;          // feat-dword lanes per edge
    constexpr int EPI = GS / L;          // edges in parallel (4)
    constexpr int GPW = 64 / GS;         // node-heads per wave
    constexpr int NB  = 4 * GPW;         // node-heads per block
    constexpr int BPH = NN2 / NB;        // blocks per head
    int h, blk;
    {
        const int r = blockIdx.x & 7, g = blockIdx.x >> 3;
        if (r < 6) {
            if (g >= MAIN) return;
            h = r; blk = g;
        } else {
            const int k = (r - 6) * G + g;
            if (k >= 6 * (BPH - MAIN)) return;
            h = k % 6; blk = MAIN + k / 6;
        }
    }
    const int wavid = threadIdx.x >> 6;
    const int lane  = threadIdx.x & 63;
    const int grp = lane / GS;           // node-head group within wave
    const int lg  = lane - grp * GS;
    const int eo = lg / L;
    const int fp = lg - eo * L;
    const int npos = blk * NB + wavid * GPW + grp;
    const int n = sorted[npos];          // window-sorted indirection

    const int s0  = off[n];
    const int deg = off[n + 1] - s0;
    const unsigned* ewp = ((h < 3) ? (ewA + (size_t)h * NE2)
                                   : (ewB + (size_t)(h - 3) * NE2)) + s0;
    const unsigned* zh = zf8 + (size_t)h * ((size_t)NN2 * L);

    float a0 = 0.f, a1 = 0.f, a2 = 0.f, a3 = 0.f, lsum = 0.f;
    for (int ib = 0; ib < deg; ib += 4 * EPI) {
        unsigned rec[4];
#pragma unroll
        for (int k = 0; k < 4; ++k) {
            const int idx = ib + k * EPI + eo;
            rec[k] = ewp[idx < deg ? idx : 0];
        }
        unsigned zz[4];
#pragma unroll
        for (int k = 0; k < 4; ++k)
            zz[k] = zh[(rec[k] & 0xFFFFu) * (unsigned)L + (unsigned)fp];
#pragma unroll
        for (int k = 0; k < 4; ++k) {
            const int idx = ib + k * EPI + eo;
            float ww = __uint_as_float(rec[k] & 0xFFFF0000u);
            ww = (idx < deg) ? ww : 0.f;
            lsum += ww;
            const f32x2 lo = __builtin_amdgcn_cvt_pk_f32_fp8((int)zz[k], false);
            const f32x2 hi = __builtin_amdgcn_cvt_pk_f32_fp8((int)zz[k], true);
            a0 = fmaf(ww, lo.x, a0);
            a1 = fmaf(ww, lo.y, a1);
            a2 = fmaf(ww, hi.x, a2);
            a3 = fmaf(ww, hi.y, a3);
        }
    }
#pragma unroll
    for (int d = L; d < GS; d <<= 1) {   // reduce within GS-group only
        a0 += __shfl_xor(a0, d);
        a1 += __shfl_xor(a1, d);
        a2 += __shfl_xor(a2, d);
        a3 += __shfl_xor(a3, d);
        lsum += __shfl_xor(lsum, d);
    }
    if (eo == 0) {
        const float inv = 1.f / (lsum + 1e-16f);
        float o0 = a0 * inv, o1 = a1 * inv, o2 = a2 * inv, o3 = a3 * inv;
        o0 = o0 > 0.f ? o0 : (__expf(o0) - 1.f);
        o1 = o1 > 0.f ? o1 : (__expf(o1) - 1.f);
        o2 = o2 > 0.f ? o2 : (__expf(o2) - 1.f);
        o3 = o3 > 0.f ? o3 : (__expf(o3) - 1.f);
        unsigned short* op = outz + (size_t)n * HF + h * Fo + 4 * fp;
        *(unsigned*)op       = (unsigned)f2bf(o0) | ((unsigned)f2bf(o1) << 16);
        *(unsigned*)(op + 2) = (unsigned)f2bf(o2) | ((unsigned)f2bf(o3) << 16);
    }
}

// ---------- layer-3 aggregation fused with sum pooling: 16-chain + win-sorted ---
// Per-chain graph select (n < N_NODES): only the single window straddling the
// graph boundary produces mixed waves; everywhere else the branch is uniform.
#define POOL_BLOCKS 3072
#define POOL_WAVES 2048
__global__ __launch_bounds__(256) void agg_pool_kernel(
        const int* __restrict__ off, const unsigned short* __restrict__ sorted,
        const unsigned* __restrict__ ewA, const unsigned* __restrict__ ewB,
        const unsigned* __restrict__ zf8, float* __restrict__ pooled) {
    __shared__ float lds[128];
    int h, slot;
    {
        const int r = blockIdx.x & 7, g = blockIdx.x >> 3;   // g in [0,384)
        if (r < 6) { h = r; slot = g; }
        else { h = g % 6; slot = 384 + (r - 6) * 64 + g / 6; }
    }
    const int wavid = threadIdx.x >> 6;
    const int ws    = slot * 4 + wavid;          // [0,2048)
    const int lane  = threadIdx.x & 63;
    const int c  = lane >> 2;                    // chain within wave, 0..15
    const int fp = lane & 3;                     // dwordx4 slice -> feats fp*16..fp*16+15
    const unsigned* ewh = (h < 3) ? (ewA + (size_t)h * NE2)
                                  : (ewB + (size_t)(h - 3) * NE2);
    const u32x4* zq = (const u32x4*)(zf8 + (size_t)h * ((size_t)NN2 * 16));

    if (threadIdx.x < 128) lds[threadIdx.x] = 0.f;
    __syncthreads();

    float p0[16], p1[16];
#pragma unroll
    for (int j = 0; j < 16; ++j) { p0[j] = 0.f; p1[j] = 0.f; }

    for (int base = ws * 16; base < NN2; base += POOL_WAVES * 16) {
        const int npos = base + c;               // 16 chains stay in one 256-window
        const int n = sorted[npos];              // window-sorted indirection
        const int s0  = off[n];
        const int deg = off[n + 1] - s0;
        int dmx = deg;
#pragma unroll
        for (int d = 4; d < 64; d <<= 1) {       // wave-max degree (~=deg after sort)
            const int o = __shfl_xor(dmx, d);
            dmx = o > dmx ? o : dmx;
        }
        const unsigned* ewp = ewh + s0;
        float acc[16];
#pragma unroll
        for (int j = 0; j < 16; ++j) acc[j] = 0.f;
        float lsum = 0.f;
        for (int ib = 0; ib < dmx; ib += 4) {
            unsigned rec[4];
#pragma unroll
            for (int k = 0; k < 4; ++k) {
                const int idx = ib + k;
                rec[k] = ewp[idx < deg ? idx : 0];
            }
            u32x4 zz[4];
#pragma unroll
            for (int k = 0; k < 4; ++k)
                zz[k] = zq[(rec[k] & 0xFFFFu) * 4u + (unsigned)fp];
#pragma unroll
            for (int k = 0; k < 4; ++k) {
                float w = __uint_as_float(rec[k] & 0xFFFF0000u);
                w = ((ib + k) < deg) ? w : 0.f;
                lsum += w;
#pragma unroll
                for (int d = 0; d < 4; ++d) {
                    const f32x2 lo = __builtin_amdgcn_cvt_pk_f32_fp8((int)zz[k][d], false);
                    const f32x2 hi = __builtin_amdgcn_cvt_pk_f32_fp8((int)zz[k][d], true);
                    acc[4 * d + 0] = fmaf(w, lo.x, acc[4 * d + 0]);
                    acc[4 * d + 1] = fmaf(w, lo.y, acc[4 * d + 1]);
                    acc[4 * d + 2] = fmaf(w, hi.x, acc[4 * d + 2]);
                    acc[4 * d + 3] = fmaf(w, hi.y, acc[4 * d + 3]);
                }
            }
        }
        {
            const float inv = 1.f / (lsum + 1e-16f);
            if (n < N_NODES) {                   // per-chain graph select
#pragma unroll
                for (int j = 0; j < 16; ++j) {
                    float o = acc[j] * inv;
                    o = o > 0.f ? o : (__expf(o) - 1.f);
                    p0[j] += o;
                }
            } else {
#pragma unroll
                for (int j = 0; j < 16; ++j) {
                    float o = acc[j] * inv;
                    o = o > 0.f ? o : (__expf(o) - 1.f);
                    p1[j] += o;
                }
            }
        }
    }
    // one butterfly per kernel: reduce pooled sums across the 16 chains
#pragma unroll
    for (int d = 4; d < 64; d <<= 1) {
#pragma unroll
        for (int j = 0; j < 16; ++j) {
            p0[j] += __shfl_xor(p0[j], d);
            p1[j] += __shfl_xor(p1[j], d);
        }
    }
    if (lane < 4) {                              // fp == lane here
#pragma unroll
        for (int j = 0; j < 16; ++j) {
            atomicAdd(&lds[fp * 16 + j], p0[j]);
            atomicAdd(&lds[64 + fp * 16 + j], p1[j]);
        }
    }
    __syncthreads();
    if (threadIdx.x < 128) {
        const int g2 = threadIdx.x >> 6;
        const int f  = threadIdx.x & 63;
        atomicAdd(&pooled[g2 * 384 + h * 64 + f], lds[threadIdx.x]);
    }
}

__global__ void zero_pooled_kernel(float* __restrict__ p) {
    const int i = blockIdx.x * 256 + threadIdx.x;
    if (i < 768) p[i] = 0.f;
}

__global__ void final_kernel(const float* __restrict__ pooled, const float* __restrict__ Wd,
                             const float* __restrict__ bd, float* __restrict__ outp) {
    __shared__ float s_ss[256], s_dot[256];
    const int t = threadIdx.x;
    float ss = 0.f, dot = 0.f;
    for (int c = t; c < 768; c += 256) {
        const float v = pooled[c];
        ss  = fmaf(v, v, ss);
        dot = fmaf(v, Wd[c], dot);
    }
    s_ss[t] = ss; s_dot[t] = dot;
    __syncthreads();
    for (int off = 128; off > 0; off >>= 1) {
        if (t < off) { s_ss[t] += s_ss[t + off]; s_dot[t] += s_dot[t + off]; }
        __syncthreads();
    }
    if (t == 0) {
        const float norm = fmaxf(sqrtf(s_ss[0]), 1e-12f);
        outp[0] = s_dot[0] / norm + bd[0];
    }
}

extern "C" void kernel_launch(void* const* d_in, const int* in_sizes, int n_in,
                              void* d_out, int out_size, void* d_ws, size_t ws_size,
                              hipStream_t stream) {
    const float* x_int = (const float*)d_in[0];
    const float* x_nh  = (const float*)d_in[1];
    const int*   ei_int = (const int*)d_in[2];
    const int*   ei_nh  = (const int*)d_in[3];
    const float* W1  = (const float*)d_in[4];
    const float* a1s = (const float*)d_in[5];
    const float* a1d = (const float*)d_in[6];
    const float* W2  = (const float*)d_in[7];
    const float* a2s = (const float*)d_in[8];
    const float* a2d = (const float*)d_in[9];
    const float* W3  = (const float*)d_in[10];
    const float* a3s = (const float*)d_in[11];
    const float* a3d = (const float*)d_in[12];
    const float* Wd  = (const float*)d_in[13];
    const float* bd  = (const float*)d_in[14];
    float* out = (float*)d_out;

    // workspace layout (16B-aligned sections); total ~63.0 MiB
    unsigned short* hbf_a = (unsigned short*)d_ws;                 // NN2*96  bf16 (11.52 MB)
    unsigned short* hbf_b = hbf_a + (size_t)NN2 * 96;              // NN2*192 bf16 (23.04 MB)
    unsigned short* wt2   = hbf_b + (size_t)NN2 * 192;             // 192*96
    unsigned short* wt3   = wt2   + (size_t)96 * 192;              // 384*192
    unsigned* zf8 = (unsigned*)(wt3 + (size_t)192 * 384);          // NN2*96 dwords (fp8, head-major)
    float* es8   = (float*)(zf8 + (size_t)NN2 * 96);               // NN2*8 ([node][head])
    float* ed8   = es8 + (size_t)NN2 * 8;                          // NN2*8
    float* pooled = ed8 + (size_t)NN2 * 8;                         // 768
    int* tmp     = (int*)(pooled + 768);                           // SCAN_NB*1024 (cnt/prefix/cursor)
    int* bsum    = tmp + SCAN_NB * 1024;                           // SCAN_NB
    int* boff    = bsum + SCAN_NB;                                 // SCAN_NB+1
    int* off     = boff + SCAN_NB + 1;                             // NN2+1
    unsigned* csrp = (unsigned*)(off + NN2 + 1);                   // NE2 u32 ({dst|src})
    unsigned short* sorted = (unsigned short*)(csrp + NE2);        // NN2 u16 (win-sorted nodes)
    unsigned char* zf8b = (unsigned char*)zf8;

    // u32 ew planes (6*NE2*4 = 23.04 MB), aliased into DEAD buffer windows:
    //  layers 1,3: all 6 planes in hbf_b; layer 2: planes 0-2 in hbf_a,
    //  planes 3-5 in zf8 tail (layer-2 z fills only first NN2*48 dwords)
    unsigned* ew13A = (unsigned*)hbf_b;
    unsigned* ew13B = ew13A + (size_t)3 * NE2;
    unsigned* ew2A  = (unsigned*)hbf_a;
    unsigned* ew2B  = zf8 + (size_t)NN2 * 48;

    zero_pooled_kernel<<<3, 256, 0, stream>>>(pooled);
    convert_wt_kernel<<<(96 * 192 + 255) / 256, 256, 0, stream>>>(W2, wt2, 96, 192);
    convert_wt_kernel<<<(192 * 384 + 255) / 256, 256, 0, stream>>>(W3, wt3, 192, 384);

    // batched CSR over both graphs
    zero_int_kernel<<<(NN2 + 255) / 256, 256, 0, stream>>>(tmp, NN2);
    hist2_kernel<<<(NE2 + 255) / 256, 256, 0, stream>>>(ei_int, ei_nh, tmp);
    scan1_kernel<<<SCAN_NB, 1024, 0, stream>>>(tmp, bsum);
    scan2_kernel<<<1, 64, 0, stream>>>(bsum, boff);
    scan3_kernel<<<SCAN_NB, 1024, 0, stream>>>(tmp, boff, off);
    scatter2_kernel<<<(NE2 + 255) / 256, 256, 0, stream>>>(ei_int, ei_nh, tmp, csrp);

    // window-local degree sort (preserves streaming locality; r11 lesson)
    winsort_kernel<<<(NN2 + 255) / 256, 256, 0, stream>>>(off, sorted);

    const int mfma_blocks = (NN2 / 16 + 3) / 4;
    const int ew_blocks = (NE2 + 255) / 256;

    // layer 1: VALU GEMM + fused es/ed + fp8 z; edge records; agg GS=16 (win-sorted)
    gemm1_es_kernel<<<dim3(NN2 / 16, 2), 64, 0, stream>>>(x_int, x_nh, W1, a1s, a1d, zf8b,
                                                          es8, ed8);
    edgew_kernel<<<ew_blocks, 256, 0, stream>>>(csrp, es8, ed8, ew13A, ew13B);
    agg_sub_kernel<96, 16, 2812, 2814><<<8 * 2814, 256, 0, stream>>>(off, sorted, ew13A,
                                                                     ew13B, zf8, hbf_a);
    // layer 2: MFMA GEMM (LDS-staged B) + fused epilogue; agg GS=32 (win-sorted)
    gemm_es_kernel<96, 192><<<mfma_blocks, 256, 0, stream>>>(hbf_a, wt2, a2s, a2d, zf8b,
                                                             es8, ed8);
    edgew_kernel<<<ew_blocks, 256, 0, stream>>>(csrp, es8, ed8, ew2A, ew2B);
    agg_sub_kernel<192, 32, 5625, 5625><<<45000, 256, 0, stream>>>(off, sorted, ew2A,
                                                                   ew2B, zf8, hbf_b);
    // layer 3: MFMA GEMM (LDS-staged B) + fused epilogue; 16-chain agg+pool (win-sorted)
    gemm_es_kernel<192, 384><<<mfma_blocks, 256, 0, stream>>>(hbf_b, wt3, a3s, a3d, zf8b,
                                                              es8, ed8);
    edgew_kernel<<<ew_blocks, 256, 0, stream>>>(csrp, es8, ed8, ew13A, ew13B);
    agg_pool_kernel<<<POOL_BLOCKS, 256, 0, stream>>>(off, sorted, ew13A, ew13B, zf8,
                                                     pooled);

    final_kernel<<<1, 256, 0, stream>>>(pooled, Wd, bd, out);
}